// Round 11
// baseline (150.777 us; speedup 1.0000x reference)
//
#include <hip/hip_runtime.h>

#define DIM 256
#define L_ 128
#define TD 64
#define NVOCAB 150
#define NB 2048

typedef float floatx4 __attribute__((ext_vector_type(4)));

__device__ __forceinline__ float dot4(float4 a, float4 b) {
    return fmaf(a.x, b.x, fmaf(a.y, b.y, fmaf(a.z, b.z, a.w * b.w)));
}

__device__ __forceinline__ float4 nt_load4(const float4* p) {
    floatx4 r = __builtin_nontemporal_load((const floatx4*)p);
    return make_float4(r.x, r.y, r.z, r.w);
}

// ---------------------------------------------------------------------------
// Kernel A: M[c][d] = (1/16) * sum_e Wq[e][c] * Wk[e][d]   (256x256)
//           plus per-vocab scalar tables (BETA=0.5 folded in):
//           rel_s[v] = 0.5 * dot(rel_emb_w[v], Wrp[0:64])
//           pos_s[v] = 0.5 * dot(pos_emb_w[v], Wrp[64:128])
// ---------------------------------------------------------------------------
__global__ __launch_bounds__(256) void prep_kernel(
    const float* __restrict__ Wk, const float* __restrict__ Wq,
    const float* __restrict__ Wrp,
    const float* __restrict__ rel_emb_w, const float* __restrict__ pos_emb_w,
    float* __restrict__ M, float* __restrict__ rel_s, float* __restrict__ pos_s)
{
    if (blockIdx.x == DIM) {
        int v = threadIdx.x;
        if (v < NVOCAB) {
            float sr = 0.f, sp = 0.f;
#pragma unroll 8
            for (int j = 0; j < TD; ++j) {
                sr = fmaf(rel_emb_w[v * TD + j], Wrp[j], sr);
                sp = fmaf(pos_emb_w[v * TD + j], Wrp[TD + j], sp);
            }
            rel_s[v] = 0.5f * sr;
            pos_s[v] = 0.5f * sp;
        }
        return;
    }
    int cc = blockIdx.x;   // uniform per block -> Wq reads become scalar loads
    int d  = threadIdx.x;
    float acc = 0.f;
#pragma unroll 16
    for (int e = 0; e < DIM; ++e)
        acc = fmaf(Wq[e * DIM + cc], Wk[e * DIM + d], acc);
    M[cc * DIM + d] = acc * (1.0f / 16.0f);   // temperature = sqrt(256) = 16
}

// ---------------------------------------------------------------------------
// Kernel B (fused): blocks [0,256): qk = hn @ M.
//                   blocks [256,1280): bias_g[b*L+l] = mask ? -1e30 : rel+pos
// ---------------------------------------------------------------------------
__global__ __launch_bounds__(256) void qk_bias_kernel(
    const float* __restrict__ hn, const float* __restrict__ M,
    const int* __restrict__ pos_ind, const int* __restrict__ rel_dt,
    const float* __restrict__ rel_s, const float* __restrict__ pos_s,
    float* __restrict__ qk, float* __restrict__ bias_g)
{
    const int t = threadIdx.x;
    if (blockIdx.x >= NB / 8) {
        int idx = (blockIdx.x - NB / 8) * 256 + t;   // [0, NB*L_) exactly
        int pi = pos_ind[idx];
        int rd = rel_dt[idx];
        bias_g[idx] = (pi == 0) ? -1e30f : (rel_s[rd] + pos_s[pi]);
        return;
    }
    __shared__ float hn_s[8][DIM];
    const int r0 = blockIdx.x * 8;
#pragma unroll
    for (int i = 0; i < 8; ++i)
        hn_s[i][t] = hn[(size_t)(r0 + i) * DIM + t];
    __syncthreads();
    float acc[8] = {0.f, 0.f, 0.f, 0.f, 0.f, 0.f, 0.f, 0.f};
#pragma unroll 8
    for (int c = 0; c < DIM; ++c) {
        float m = M[c * DIM + t];
#pragma unroll
        for (int r = 0; r < 8; ++r)
            acc[r] = fmaf(hn_s[r][c], m, acc[r]);
    }
#pragma unroll
    for (int r = 0; r < 8; ++r)
        qk[(size_t)(r0 + r) * DIM + t] = acc[r];
}

// ---------------------------------------------------------------------------
// Kernel C: PERSISTENT pipelined burst. 512 blocks (exactly 2/CU) x 512
// threads; block bid processes b = bid, bid+512, bid+1024, bid+1536.
// Same in-block layout as R3: 8 waves, 32 groups of 16 lanes, group
// grp = 4w+g owns rows {r0+4k}, lane c holds 16 cols. The next b's 16
// float4 burst issues right after the weighted accumulate (last use of v)
// and BEFORE the merge barriers -> loads stay in flight through the tail.
// No dispatch churn. nt loads: stream read once, skip cache allocation.
// ---------------------------------------------------------------------------
__global__ __launch_bounds__(512, 4) void attn_main(
    const float* __restrict__ outp, const float* __restrict__ qk,
    const float* __restrict__ bias_g, float* __restrict__ y)
{
    const int t    = threadIdx.x;
    const int w    = t >> 6;
    const int lane = t & 63;
    const int g    = lane >> 4;
    const int c    = lane & 15;
    const int grp  = (w << 2) | g;

    __shared__ float mG[32];
    __shared__ float dG[32];
    __shared__ float red[32][DIM];

    const int r0   = (w << 4) | g;
    const int base = r0 * 64 + c;

    int b = blockIdx.x;

    // ---- initial burst for b ----
    const float4* __restrict__ src = (const float4*)outp + (size_t)b * (L_ * 64);
    float4 v[16];
#pragma unroll
    for (int k = 0; k < 4; ++k)
#pragma unroll
        for (int j = 0; j < 4; ++j)
            v[k * 4 + j] = nt_load4(&src[base + k * 256 + j * 16]);

    for (int it = 0; it < 4; ++it) {
        // qk fragment (L2-hot) and this group's 4 row biases
        const float4* __restrict__ qp = (const float4*)qk + (size_t)b * 64;
        float4 q[4];
#pragma unroll
        for (int j = 0; j < 4; ++j) q[j] = qp[c + j * 16];
        const float* __restrict__ bp = bias_g + (size_t)b * L_ + r0;
        float bi[4];
#pragma unroll
        for (int k = 0; k < 4; ++k) bi[k] = bp[4 * k];

        // ---- 4 logits: partial dots + 16-lane allreduce ----
        float lg[4];
#pragma unroll
        for (int k = 0; k < 4; ++k) {
            float p = dot4(v[k * 4 + 0], q[0]) + dot4(v[k * 4 + 1], q[1]) +
                      dot4(v[k * 4 + 2], q[2]) + dot4(v[k * 4 + 3], q[3]);
            p += __shfl_xor(p, 1);
            p += __shfl_xor(p, 2);
            p += __shfl_xor(p, 4);
            p += __shfl_xor(p, 8);
            lg[k] = p + bi[k];
        }

        // ---- group-local softmax ----
        const float m = fmaxf(fmaxf(lg[0], lg[1]), fmaxf(lg[2], lg[3]));
        float we[4];
        float d = 0.f;
#pragma unroll
        for (int k = 0; k < 4; ++k) { we[k] = __expf(lg[k] - m); d += we[k]; }

        // ---- weighted accumulate (last consumer of v) ----
        float4 o[4];
#pragma unroll
        for (int j = 0; j < 4; ++j) o[j] = make_float4(0.f, 0.f, 0.f, 0.f);
#pragma unroll
        for (int k = 0; k < 4; ++k)
#pragma unroll
            for (int j = 0; j < 4; ++j) {
                o[j].x = fmaf(we[k], v[k * 4 + j].x, o[j].x);
                o[j].y = fmaf(we[k], v[k * 4 + j].y, o[j].y);
                o[j].z = fmaf(we[k], v[k * 4 + j].z, o[j].z);
                o[j].w = fmaf(we[k], v[k * 4 + j].w, o[j].w);
            }

        // ---- issue NEXT b's burst before the merge barriers ----
        const int bn = b + 512;
        if (it < 3) {
            const float4* __restrict__ srcn =
                (const float4*)outp + (size_t)bn * (L_ * 64);
#pragma unroll
            for (int k = 0; k < 4; ++k)
#pragma unroll
                for (int j = 0; j < 4; ++j)
                    v[k * 4 + j] = nt_load4(&srcn[base + k * 256 + j * 16]);
        }

        // ---- merge 32 group states (loads for bn remain in flight) ----
        if (c == 0) { mG[grp] = m; dG[grp] = d; }
        __syncthreads();

        float Mx = -1e30f;
#pragma unroll
        for (int i = 0; i < 32; ++i) Mx = fmaxf(Mx, mG[i]);  // LDS broadcasts
        float term = (lane < 32) ? __expf(mG[lane] - Mx) * dG[lane] : 0.f;
#pragma unroll
        for (int off = 32; off >= 1; off >>= 1) term += __shfl_xor(term, off, 64);
        const float f = __expf(m - Mx) / term;

        float4* rw = (float4*)(&red[grp][0]);
#pragma unroll
        for (int j = 0; j < 4; ++j)
            rw[c + j * 16] = make_float4(o[j].x * f, o[j].y * f,
                                         o[j].z * f, o[j].w * f);
        __syncthreads();

        if (t < DIM) {
            float s = 0.f;
#pragma unroll
            for (int gg = 0; gg < 32; ++gg) s += red[gg][t];  // 2-way banked
            y[(size_t)b * DIM + t] = s;
        }
        __syncthreads();   // protect mG/dG/red reuse next iteration
        b = bn;
    }
}

// ---------------------------------------------------------------------------
extern "C" void kernel_launch(void* const* d_in, const int* in_sizes, int n_in,
                              void* d_out, int out_size, void* d_ws, size_t ws_size,
                              hipStream_t stream)
{
    const float* out_t     = (const float*)d_in[0];  // [B, L, DIM]
    const float* hn        = (const float*)d_in[1];  // [B, DIM]
    const int*   pos_ind   = (const int*)  d_in[2];  // [B, L]
    const int*   rel_dt    = (const int*)  d_in[3];  // [B, L]
    // d_in[4] = abs_dt (unused)
    const float* pos_emb_w = (const float*)d_in[5];  // [VOCAB, TD]
    const float* rel_emb_w = (const float*)d_in[6];  // [VOCAB, TD]
    const float* Wk        = (const float*)d_in[7];  // [DIM, DIM]
    const float* Wq        = (const float*)d_in[8];  // [DIM, DIM]
    const float* Wrp       = (const float*)d_in[9];  // [1, 2*TD]

    float* y = (float*)d_out;                        // [B, DIM] fp32

    // ws layout (floats): M[65536] | qk[NB*DIM] | rel_s[256] | pos_s[256] | bias_g[NB*L]
    float* M      = (float*)d_ws;
    float* qk     = M + DIM * DIM;
    float* rel_s  = qk + (size_t)NB * DIM;
    float* pos_s  = rel_s + 256;
    float* bias_g = pos_s + 256;

    prep_kernel<<<DIM + 1, 256, 0, stream>>>(Wk, Wq, Wrp, rel_emb_w, pos_emb_w,
                                             M, rel_s, pos_s);
    qk_bias_kernel<<<NB / 8 + (NB * L_) / 256, 256, 0, stream>>>(
        hn, M, pos_ind, rel_dt, rel_s, pos_s, qk, bias_g);
    attn_main<<<512, 512, 0, stream>>>(out_t, qk, bias_g, y);
}